// Round 6
// baseline (464.396 us; speedup 1.0000x reference)
//
#include <hip/hip_runtime.h>

typedef unsigned short u16;
typedef unsigned int u32;
typedef __bf16 bf16x8 __attribute__((ext_vector_type(8)));
typedef float f32x4 __attribute__((ext_vector_type(4)));

#define MFMA16(a,b,c) __builtin_amdgcn_mfma_f32_16x16x32_bf16((a),(b),(c),0,0,0)

__device__ __forceinline__ u16 f2bf(float x) {
  u32 u = __float_as_uint(x);
  u32 r = (u + 0x7fffu + ((u >> 16) & 1u)) >> 16;
  return (u16)r;
}

// branch-free erf-based GELU (A&S 7.1.26, |err| <= 1.5e-7), fast rcp
__device__ __forceinline__ float gelu_f(float v) {
  float u = v * 0.70710678118654752f;
  float a = fabsf(u);
  float t = __builtin_amdgcn_rcpf(1.f + 0.3275911f * a);
  float p = t * (0.254829592f + t * (-0.284496736f + t * (1.421413741f +
            t * (-1.453152027f + t * 1.061405429f))));
  float e = __expf(-u * u);
  float er = 1.f - p * e;
  er = (u < 0.f) ? -er : er;
  return 0.5f * v * (1.f + er);
}

// ---------------- weight -> bf16 MFMA-fragment order ----------------
// Fragment f holds the B-operand tile (n-tile of 16, k-tile of 32) for
// mfma_f32_16x16x32_bf16: lane ln holds B[n = nt*16 + (ln&15)][k = kt*32 +
// (ln>>4)*8 + e], stored contiguously at wf[(f<<9) + (ln<<3) + e].
__global__ __launch_bounds__(256) void prep_weights(
    const float* __restrict__ qkv_w, const float* __restrict__ proj_w,
    const float* __restrict__ fc1_w, const float* __restrict__ fc2_w,
    u16* __restrict__ qkv_wf, u16* __restrict__ proj_wf,
    u16* __restrict__ fc1_wf, u16* __restrict__ fc2_wf) {
  int t0 = blockIdx.x * 256 + threadIdx.x;
  int stride = gridDim.x * 256;
  for (int i = t0; i < 36 * 6 * 512; i += stride) {
    int f = i >> 9, ln = (i >> 3) & 63, e = i & 7;
    int ct = f / 6, kc = f - ct * 6;
    int n = ct * 16 + (ln & 15), k = kc * 32 + (ln >> 4) * 8 + e;
    qkv_wf[i] = f2bf(qkv_w[k * 576 + n]);
  }
  for (int i = t0; i < 12 * 6 * 512; i += stride) {
    int f = i >> 9, ln = (i >> 3) & 63, e = i & 7;
    int ct = f / 6, kc = f - ct * 6;
    int n = ct * 16 + (ln & 15), k = kc * 32 + (ln >> 4) * 8 + e;
    proj_wf[i] = f2bf(proj_w[k * 192 + n]);
  }
  for (int i = t0; i < 48 * 6 * 512; i += stride) {
    int f = i >> 9, ln = (i >> 3) & 63, e = i & 7;
    int ctg = f / 6, kc = f - ctg * 6;
    int n = ctg * 16 + (ln & 15), k = kc * 32 + (ln >> 4) * 8 + e;
    fc1_wf[i] = f2bf(fc1_w[k * 768 + n]);
  }
  for (int i = t0; i < 24 * 12 * 512; i += stride) {
    int f = i >> 9, ln = (i >> 3) & 63, e = i & 7;
    int g2 = f / 12, ct = f - g2 * 12;
    int n = ct * 16 + (ln & 15), k = g2 * 32 + (ln >> 4) * 8 + e;
    fc2_wf[i] = f2bf(fc2_w[k * 192 + n]);
  }
}

// ---------------- fused LN1(+shift/window gather) + QKV GEMM ----------------
__global__ __launch_bounds__(256) void qkv_ln_kernel(
    const float* __restrict__ x, const float* __restrict__ g,
    const float* __restrict__ bb,
    const u16* __restrict__ qkv_wf, const float* __restrict__ qkv_b,
    u16* __restrict__ qkvb, int rowbase, int wbase) {
  __shared__ __align__(16) u16 sA[128 * 200];
  const int tid = threadIdx.x;
  const int r0 = rowbase + blockIdx.x * 128;

  {
    int r = tid >> 1, half = tid & 1;
    int gr = r0 + r;
    int w = gr / 49, n = gr - w * 49;
    int b = w >> 6, wi = w & 63;
    int rr = n / 7, cc = n - rr * 7;
    int hh = (wi >> 3) * 7 + rr + 3; if (hh >= 56) hh -= 56;
    int ww = (wi & 7) * 7 + cc + 3; if (ww >= 56) ww -= 56;
    const float* src = x + ((size_t)b * 3136 + hh * 56 + ww) * 192 + half * 96;
    float s1 = 0.f, s2 = 0.f;
    #pragma unroll
    for (int i = 0; i < 24; i++) {
      float4 v = ((const float4*)src)[i];
      s1 += v.x + v.y + v.z + v.w;
      s2 += v.x * v.x + v.y * v.y + v.z * v.z + v.w * v.w;
    }
    s1 += __shfl_xor(s1, 1);
    s2 += __shfl_xor(s2, 1);
    float mu = s1 * (1.f / 192.f);
    float var = s2 * (1.f / 192.f) - mu * mu;
    float rs = rsqrtf(var + 1e-5f);
    u16* drow = sA + r * 200 + half * 96;
    #pragma unroll
    for (int i = 0; i < 24; i++) {
      float4 v = ((const float4*)src)[i];
      int c = half * 96 + i * 4;
      ushort4 o;
      o.x = f2bf((v.x - mu) * rs * g[c + 0] + bb[c + 0]);
      o.y = f2bf((v.y - mu) * rs * g[c + 1] + bb[c + 1]);
      o.z = f2bf((v.z - mu) * rs * g[c + 2] + bb[c + 2]);
      o.w = f2bf((v.w - mu) * rs * g[c + 3] + bb[c + 3]);
      *((ushort4*)(drow + i * 4)) = o;
    }
  }
  __syncthreads();

  const int wv = tid >> 6, ln = tid & 63, lrow = ln & 15, quad = ln >> 4;
  const int ln8 = ln << 3;

  u32 qkoff[8], voff[8];
  #pragma unroll
  for (int rt = 0; rt < 2; rt++) {
    #pragma unroll
    for (int reg = 0; reg < 4; reg++) {
      int grow = r0 + 32 * wv + 16 * rt + quad * 4 + reg;
      int w_ = grow / 49, n_ = grow - w_ * 49;
      u32 wb = (u32)(w_ - wbase) * 29568u;
      qkoff[rt * 4 + reg] = wb + (u32)n_ * 32u;
      voff[rt * 4 + reg] = wb + (u32)n_;
    }
  }

  for (int ct = 0; ct < 36; ct++) {
    f32x4 acc0 = (f32x4){0.f, 0.f, 0.f, 0.f};
    f32x4 acc1 = (f32x4){0.f, 0.f, 0.f, 0.f};
    #pragma unroll
    for (int kc = 0; kc < 6; kc++) {
      bf16x8 a0 = *(const bf16x8*)(sA + (32 * wv + lrow) * 200 + kc * 32 + quad * 8);
      bf16x8 a1 = *(const bf16x8*)(sA + (32 * wv + 16 + lrow) * 200 + kc * 32 + quad * 8);
      bf16x8 bw = *(const bf16x8*)(qkv_wf + ((ct * 6 + kc) << 9) + ln8);
      acc0 = MFMA16(a0, bw, acc0);
      acc1 = MFMA16(a1, bw, acc1);
    }
    int sec = ct / 12, ccc = ct - sec * 12;
    int head = ccc >> 1, d0 = (ccc & 1) * 16;
    int col = d0 + lrow;
    float bias = qkv_b[sec * 192 + head * 32 + col];
    u32 hoff = (u32)head * 4928u;
    if (sec < 2) {
      u32 coff = hoff + (u32)sec * 1568u + (u32)col;
      #pragma unroll
      for (int reg = 0; reg < 4; reg++) {
        qkvb[qkoff[reg] + coff] = f2bf(acc0[reg] + bias);
        qkvb[qkoff[4 + reg] + coff] = f2bf(acc1[reg] + bias);
      }
    } else {
      u32 coff = hoff + 3136u + (u32)col * 56u;
      #pragma unroll
      for (int reg = 0; reg < 4; reg++) {
        qkvb[voff[reg] + coff] = f2bf(acc0[reg] + bias);
        qkvb[voff[4 + reg] + coff] = f2bf(acc1[reg] + bias);
      }
    }
  }
}

// ---------------- window attention: 1 block/window, 1 wave/head ----------------
__global__ __launch_bounds__(384) void attn2_kernel(
    const u16* __restrict__ qkvb, u16* __restrict__ attnout, int wbase) {
  __shared__ __align__(16) u16 sP[6 * 64 * 72];
  const int tid = threadIdx.x;
  const int wv = tid >> 6;
  const int ln = tid & 63;
  const int lrow = ln & 15;
  const int quad = ln >> 4;
  const int wl = blockIdx.x;
  const int w = wbase + wl;
  const int wi = w & 63;
  const int wr = wi >> 3, wc = wi & 7;
  const u16* base = qkvb + (size_t)(wl * 6 + wv) * 4928;
  u16* sPw = sP + wv * (64 * 72);
  const f32x4 zero4 = {0.f, 0.f, 0.f, 0.f};

  bf16x8 kf[4];
  #pragma unroll
  for (int rt = 0; rt < 4; rt++)
    kf[rt] = *(const bf16x8*)(base + 1568 + (16 * rt + lrow) * 32 + quad * 8);
  f32x4 S[4][4];
  #pragma unroll
  for (int ct = 0; ct < 4; ct++) {
    bf16x8 qf = *(const bf16x8*)(base + (16 * ct + lrow) * 32 + quad * 8);
    #pragma unroll
    for (int rt = 0; rt < 4; rt++)
      S[rt][ct] = MFMA16(kf[rt], qf, zero4);
  }

  int hbn[4], wbn[4];
  #pragma unroll
  for (int ct = 0; ct < 4; ct++) {
    int n = 16 * ct + lrow;
    int rn = (n * 9363) >> 16;
    int cn = n - 7 * rn;
    hbn[ct] = (wr < 7) ? 0 : ((rn >= 4) ? 2 : 1);
    wbn[ct] = (wc < 7) ? 0 : ((cn >= 4) ? 2 : 1);
  }

  const float scale = 0.17677669529663687f;
  float mx[4] = {-1e30f, -1e30f, -1e30f, -1e30f};
  #pragma unroll
  for (int rt = 0; rt < 4; rt++) {
    #pragma unroll
    for (int reg = 0; reg < 4; reg++) {
      int m = 16 * rt + quad * 4 + reg;
      int rm = (m * 9363) >> 16;
      int cm = m - 7 * rm;
      int hbm = (wr < 7) ? 0 : ((rm >= 4) ? 2 : 1);
      int wbm = (wc < 7) ? 0 : ((cm >= 4) ? 2 : 1);
      bool padm = (m >= 49);
      #pragma unroll
      for (int ct = 0; ct < 4; ct++) {
        float sv = S[rt][ct][reg] * scale +
                   (((hbm != hbn[ct]) || (wbm != wbn[ct])) ? -100.f : 0.f);
        sv = padm ? -1e30f : sv;
        S[rt][ct][reg] = sv;
        mx[ct] = fmaxf(mx[ct], sv);
      }
    }
  }
  #pragma unroll
  for (int ct = 0; ct < 4; ct++) {
    mx[ct] = fmaxf(mx[ct], __shfl_xor(mx[ct], 16));
    mx[ct] = fmaxf(mx[ct], __shfl_xor(mx[ct], 32));
  }
  float sum[4] = {0.f, 0.f, 0.f, 0.f};
  #pragma unroll
  for (int rt = 0; rt < 4; rt++)
    #pragma unroll
    for (int reg = 0; reg < 4; reg++)
      #pragma unroll
      for (int ct = 0; ct < 4; ct++) {
        float e = __expf(S[rt][ct][reg] - mx[ct]);
        S[rt][ct][reg] = e;
        sum[ct] += e;
      }
  float inv[4];
  #pragma unroll
  for (int ct = 0; ct < 4; ct++) {
    sum[ct] += __shfl_xor(sum[ct], 16);
    sum[ct] += __shfl_xor(sum[ct], 32);
    inv[ct] = __builtin_amdgcn_rcpf(sum[ct]);
  }

  #pragma unroll
  for (int rt = 0; rt < 4; rt++) {
    #pragma unroll
    for (int ct = 0; ct < 4; ct++) {
      ushort4 o;
      o.x = f2bf(S[rt][ct][0] * inv[ct]);
      o.y = f2bf(S[rt][ct][1] * inv[ct]);
      o.z = f2bf(S[rt][ct][2] * inv[ct]);
      o.w = f2bf(S[rt][ct][3] * inv[ct]);
      *((ushort4*)(sPw + (16 * ct + lrow) * 72 + 16 * rt + quad * 4)) = o;
    }
  }

  f32x4 accO[4][2];
  #pragma unroll
  for (int rt = 0; rt < 4; rt++)
    #pragma unroll
    for (int cd = 0; cd < 2; cd++) accO[rt][cd] = zero4;
  #pragma unroll
  for (int kc = 0; kc < 2; kc++) {
    bf16x8 vf[2];
    #pragma unroll
    for (int cd = 0; cd < 2; cd++)
      vf[cd] = *(const bf16x8*)(base + 3136 + (16 * cd + lrow) * 56 + kc * 32 + quad * 8);
    #pragma unroll
    for (int rt = 0; rt < 4; rt++) {
      bf16x8 af = *(const bf16x8*)(sPw + (16 * rt + lrow) * 72 + kc * 32 + quad * 8);
      #pragma unroll
      for (int cd = 0; cd < 2; cd++)
        accO[rt][cd] = MFMA16(af, vf[cd], accO[rt][cd]);
    }
  }

  #pragma unroll
  for (int rt = 0; rt < 4; rt++) {
    #pragma unroll
    for (int reg = 0; reg < 4; reg++) {
      int n = 16 * rt + quad * 4 + reg;
      if (n < 49) {
        #pragma unroll
        for (int cd = 0; cd < 2; cd++)
          attnout[(size_t)(w * 49 + n) * 192 + wv * 32 + 16 * cd + lrow] =
              f2bf(accO[rt][cd][reg]);
      }
    }
  }
}

// ---------------- fused proj + LN2 + MLP + residual + scatter ----------------
// 256 thr, 64 rows/block, column-split (wave owns 48 cols of all 64 rows).
// Register prefetch: proj weights pb[18] before staging barrier, fc1b/fc2b
// one phase ahead. xr residual stays in registers (AGPR-backed) end-to-end;
// single fused epilogue write.
__global__ __launch_bounds__(256, 3) void projmlp_kernel(
    const u16* __restrict__ attnout, const u16* __restrict__ proj_wf,
    const float* __restrict__ proj_b,
    const float* __restrict__ g, const float* __restrict__ bb,
    const u16* __restrict__ fc1_wf, const float* __restrict__ fc1_b,
    const u16* __restrict__ fc2_wf, const float* __restrict__ fc2_b,
    float* __restrict__ out) {
  __shared__ __align__(16) u16 sA[64 * 200];
  __shared__ __align__(16) u16 sT[2 * 64 * 72];
  __shared__ __align__(16) float sStat[64 * 8];
  const int tid = threadIdx.x;
  const int wv = tid >> 6, ln = tid & 63, lrow = ln & 15, quad = ln >> 4;
  const int ln8 = ln << 3;
  const int r0 = blockIdx.x * 64;
  const f32x4 zero4 = {0.f, 0.f, 0.f, 0.f};

  // prefetch all proj B-fragments (18 x 4 VGPR) before the staging barrier
  bf16x8 pb[18];
  #pragma unroll
  for (int ct = 0; ct < 3; ct++)
    #pragma unroll
    for (int kc = 0; kc < 6; kc++)
      pb[ct * 6 + kc] =
          *(const bf16x8*)(proj_wf + (((wv * 3 + ct) * 6 + kc) << 9) + ln8);

  // stage attnout rows -> sA
  {
    const u32* src = (const u32*)(attnout + (size_t)r0 * 192);
    u32* dst = (u32*)sA;
    #pragma unroll
    for (int i = 0; i < 24; i++) {
      int idx = tid + i * 256;
      int r = idx / 96, c = idx - r * 96;
      dst[r * 100 + c] = src[idx];
    }
  }
  __syncthreads();   // B1

  // proj GEMM from registers
  f32x4 xr[4][3];
  #pragma unroll
  for (int rt = 0; rt < 4; rt++)
    #pragma unroll
    for (int ct = 0; ct < 3; ct++) xr[rt][ct] = zero4;
  #pragma unroll
  for (int kc = 0; kc < 6; kc++) {
    bf16x8 af[4];
    #pragma unroll
    for (int rt = 0; rt < 4; rt++)
      af[rt] = *(const bf16x8*)(sA + (16 * rt + lrow) * 200 + kc * 32 + quad * 8);
    #pragma unroll
    for (int ct = 0; ct < 3; ct++)
      #pragma unroll
      for (int rt = 0; rt < 4; rt++)
        xr[rt][ct] = MFMA16(af[rt], pb[ct * 6 + kc], xr[rt][ct]);
  }
  #pragma unroll
  for (int ct = 0; ct < 3; ct++) {
    float pbias = proj_b[wv * 48 + ct * 16 + lrow];
    #pragma unroll
    for (int rt = 0; rt < 4; rt++) {
      xr[rt][ct][0] += pbias; xr[rt][ct][1] += pbias;
      xr[rt][ct][2] += pbias; xr[rt][ct][3] += pbias;
    }
  }

  // prefetch first MLP weights (consumed after B3/B4)
  bf16x8 fc1b[6], fc2b[6];
  #pragma unroll
  for (int kc = 0; kc < 6; kc++)
    fc1b[kc] = *(const bf16x8*)(fc1_wf + (((0 * 4 + wv) * 6 + kc) << 9) + ln8);
  #pragma unroll
  for (int kc2 = 0; kc2 < 2; kc2++)
    #pragma unroll
    for (int ct = 0; ct < 3; ct++)
      fc2b[kc2 * 3 + ct] = *(const bf16x8*)(fc2_wf +
          (((0 * 2 + kc2) * 12 + wv * 3 + ct) << 9) + ln8);

  // LN2 stats (partial 48 cols/wave, exchange via LDS)
  {
    float ps1[4][4], ps2[4][4];
    #pragma unroll
    for (int rt = 0; rt < 4; rt++)
      #pragma unroll
      for (int reg = 0; reg < 4; reg++) {
        float a = xr[rt][0][reg] + xr[rt][1][reg] + xr[rt][2][reg];
        float b = xr[rt][0][reg] * xr[rt][0][reg] +
                  xr[rt][1][reg] * xr[rt][1][reg] +
                  xr[rt][2][reg] * xr[rt][2][reg];
        ps1[rt][reg] = a; ps2[rt][reg] = b;
      }
    #pragma unroll
    for (int m = 1; m <= 8; m <<= 1)
      #pragma unroll
      for (int rt = 0; rt < 4; rt++)
        #pragma unroll
        for (int reg = 0; reg < 4; reg++) {
          ps1[rt][reg] += __shfl_xor(ps1[rt][reg], m);
          ps2[rt][reg] += __shfl_xor(ps2[rt][reg], m);
        }
    if (lrow == 0) {
      #pragma unroll
      for (int rt = 0; rt < 4; rt++)
        #pragma unroll
        for (int reg = 0; reg < 4; reg++) {
          int row = 16 * rt + 4 * quad + reg;
          *(float2*)&sStat[row * 8 + wv * 2] =
              make_float2(ps1[rt][reg], ps2[rt][reg]);
        }
    }
  }
  __syncthreads();   // B2

  // finish LN2 -> sA (normalized bf16 overwrites staged input)
  {
    float gc[3], bc[3];
    #pragma unroll
    for (int ct = 0; ct < 3; ct++) {
      int col = wv * 48 + ct * 16 + lrow;
      gc[ct] = g[col]; bc[ct] = bb[col];
    }
    #pragma unroll
    for (int rt = 0; rt < 4; rt++) {
      float mu_[4], rs_[4];
      #pragma unroll
      for (int reg = 0; reg < 4; reg++) {
        int row = 16 * rt + 4 * quad + reg;
        f32x4 q0 = *(const f32x4*)&sStat[row * 8];
        f32x4 q1 = *(const f32x4*)&sStat[row * 8 + 4];
        float s1 = q0[0] + q0[2] + q1[0] + q1[2];
        float s2 = q0[1] + q0[3] + q1[1] + q1[3];
        float mu = s1 * (1.f / 192.f);
        float var = s2 * (1.f / 192.f) - mu * mu;
        mu_[reg] = mu; rs_[reg] = rsqrtf(var + 1e-5f);
      }
      #pragma unroll
      for (int ct = 0; ct < 3; ct++) {
        int col = wv * 48 + ct * 16 + lrow;
        #pragma unroll
        for (int reg = 0; reg < 4; reg++) {
          int row = 16 * rt + 4 * quad + reg;
          sA[row * 200 + col] =
              f2bf((xr[rt][ct][reg] - mu_[reg]) * rs_[reg] * gc[ct] + bc[ct]);
        }
      }
    }
  }
  __syncthreads();   // B3

  f32x4 accO[4][3];
  #pragma unroll
  for (int rt = 0; rt < 4; rt++)
    #pragma unroll
    for (int ct = 0; ct < 3; ct++) accO[rt][ct] = zero4;

  auto FC1 = [&](int ch, u16* dst) {
    f32x4 accT[4] = {zero4, zero4, zero4, zero4};
    #pragma unroll
    for (int kc = 0; kc < 6; kc++) {
      bf16x8 af[4];
      #pragma unroll
      for (int rt = 0; rt < 4; rt++)
        af[rt] = *(const bf16x8*)(sA + (16 * rt + lrow) * 200 + kc * 32 + quad * 8);
      #pragma unroll
      for (int rt = 0; rt < 4; rt++)
        accT[rt] = MFMA16(af[rt], fc1b[kc], accT[rt]);
    }
    float b1 = fc1_b[ch * 64 + wv * 16 + lrow];
    #pragma unroll
    for (int rt = 0; rt < 4; rt++)
      #pragma unroll
      for (int reg = 0; reg < 4; reg++) {
        float v = accT[rt][reg] + b1;
        dst[(16 * rt + 4 * quad + reg) * 72 + wv * 16 + lrow] = f2bf(gelu_f(v));
      }
  };
  auto FC2 = [&](const u16* src) {
    #pragma unroll
    for (int kc2 = 0; kc2 < 2; kc2++) {
      bf16x8 ta[4];
      #pragma unroll
      for (int rt = 0; rt < 4; rt++)
        ta[rt] = *(const bf16x8*)(src + (16 * rt + lrow) * 72 + kc2 * 32 + quad * 8);
      #pragma unroll
      for (int ct = 0; ct < 3; ct++)
        #pragma unroll
        for (int rt = 0; rt < 4; rt++)
          accO[rt][ct] = MFMA16(ta[rt], fc2b[kc2 * 3 + ct], accO[rt][ct]);
    }
  };

  FC1(0, sT);          // consumes fc1b(0)
  __syncthreads();     // B4
  for (int ch = 0; ch < 12; ch++) {
    if (ch < 11) {     // prefetch fc1 weights for ch+1, pinned before FC2
      #pragma unroll
      for (int kc = 0; kc < 6; kc++)
        fc1b[kc] = *(const bf16x8*)(fc1_wf +
            ((((ch + 1) * 4 + wv) * 6 + kc) << 9) + ln8);
      __builtin_amdgcn_sched_barrier(0);
    }
    const u16* cur = sT + (ch & 1) * (64 * 72);
    u16* nxt = sT + ((ch + 1) & 1) * (64 * 72);
    FC2(cur);          // consumes fc2b(ch)
    if (ch < 11) {     // prefetch fc2 weights for ch+1 (crosses the barrier)
      #pragma unroll
      for (int kc2 = 0; kc2 < 2; kc2++)
        #pragma unroll
        for (int ct = 0; ct < 3; ct++)
          fc2b[kc2 * 3 + ct] = *(const bf16x8*)(fc2_wf +
              ((((ch + 1) * 2 + kc2) * 12 + wv * 3 + ct) << 9) + ln8);
      FC1(ch + 1, nxt);  // consumes fc1b(ch+1) prefetched above
    }
    __syncthreads();
  }

  // epilogue: single fused write out = xr + accO + fc2_b (scattered)
  float fb[3];
  #pragma unroll
  for (int ct = 0; ct < 3; ct++) fb[ct] = fc2_b[wv * 48 + ct * 16 + lrow];
  #pragma unroll
  for (int rt = 0; rt < 4; rt++) {
    #pragma unroll
    for (int reg = 0; reg < 4; reg++) {
      int gr = r0 + 16 * rt + 4 * quad + reg;
      int w = gr / 49, n = gr - w * 49;
      int b = w >> 6, wi = w & 63;
      int rr = n / 7;
      int hh = (wi >> 3) * 7 + rr + 3; if (hh >= 56) hh -= 56;
      int ww = (wi & 7) * 7 + (n - rr * 7) + 3; if (ww >= 56) ww -= 56;
      float* orow = out + ((size_t)b * 3136 + hh * 56 + ww) * 192;
      #pragma unroll
      for (int ct = 0; ct < 3; ct++) {
        int col = wv * 48 + ct * 16 + lrow;
        orow[col] = xr[rt][ct][reg] + accO[rt][ct][reg] + fb[ct];
      }
    }
  }
}

extern "C" void kernel_launch(void* const* d_in, const int* in_sizes, int n_in,
                              void* d_out, int out_size, void* d_ws, size_t ws_size,
                              hipStream_t stream) {
  const float* x      = (const float*)d_in[0];
  const float* qkv_w  = (const float*)d_in[1];
  const float* qkv_b  = (const float*)d_in[2];
  const float* proj_w = (const float*)d_in[3];
  const float* proj_b = (const float*)d_in[4];
  const float* n1_g   = (const float*)d_in[5];
  const float* n1_b   = (const float*)d_in[6];
  const float* n2_g   = (const float*)d_in[7];
  const float* n2_b   = (const float*)d_in[8];
  const float* fc1_w  = (const float*)d_in[9];
  const float* fc1_b  = (const float*)d_in[10];
  const float* fc2_w  = (const float*)d_in[11];
  const float* fc2_b  = (const float*)d_in[12];
  float* out = (float*)d_out;
  char* ws = (char*)d_ws;

  // workspace layout (bytes)
  u16* qkvb    = (u16*)(ws + 0);            // 60,555,264
  u16* attnout = (u16*)(ws + 60555264);     // 38,535,168 -> ends 99,090,432
  u16* qkv_wf  = (u16*)(ws + 99090432);     // 221,184
  u16* proj_wf = (u16*)(ws + 99311616);     // 73,728
  u16* fc1_wf  = (u16*)(ws + 99385344);     // 294,912
  u16* fc2_wf  = (u16*)(ws + 99680256);     // 294,912 -> ends 99,975,168

  prep_weights<<<256, 256, 0, stream>>>(qkv_w, proj_w, fc1_w, fc2_w,
                                        qkv_wf, proj_wf, fc1_wf, fc2_wf);
  for (int hf = 0; hf < 2; hf++) {
    qkv_ln_kernel<<<392, 256, 0, stream>>>(x, n1_g, n1_b, qkv_wf, qkv_b,
                                           qkvb, hf * 50176, hf * 1024);
    attn2_kernel<<<1024, 384, 0, stream>>>(qkvb, attnout, hf * 1024);
  }
  projmlp_kernel<<<1568, 256, 0, stream>>>(attnout, proj_wf, proj_b,
                                           n2_g, n2_b, fc1_wf, fc1_b,
                                           fc2_wf, fc2_b, out);
}

// Round 7
// 441.545 us; speedup vs baseline: 1.0518x; 1.0518x over previous
//
#include <hip/hip_runtime.h>

typedef unsigned short u16;
typedef unsigned int u32;
typedef __bf16 bf16x8 __attribute__((ext_vector_type(8)));
typedef float f32x4 __attribute__((ext_vector_type(4)));

#define MFMA16(a,b,c) __builtin_amdgcn_mfma_f32_16x16x32_bf16((a),(b),(c),0,0,0)

__device__ __forceinline__ u16 f2bf(float x) {
  u32 u = __float_as_uint(x);
  u32 r = (u + 0x7fffu + ((u >> 16) & 1u)) >> 16;
  return (u16)r;
}

// branch-free erf-based GELU (A&S 7.1.26, |err| <= 1.5e-7), fast rcp
__device__ __forceinline__ float gelu_f(float v) {
  float u = v * 0.70710678118654752f;
  float a = fabsf(u);
  float t = __builtin_amdgcn_rcpf(1.f + 0.3275911f * a);
  float p = t * (0.254829592f + t * (-0.284496736f + t * (1.421413741f +
            t * (-1.453152027f + t * 1.061405429f))));
  float e = __expf(-u * u);
  float er = 1.f - p * e;
  er = (u < 0.f) ? -er : er;
  return 0.5f * v * (1.f + er);
}

// ---------------- weight -> bf16 MFMA-fragment order ----------------
// Fragment f holds the B-operand tile (n-tile of 16, k-tile of 32) for
// mfma_f32_16x16x32_bf16: lane ln holds B[n = nt*16 + (ln&15)][k = kt*32 +
// (ln>>4)*8 + e], stored contiguously at wf[(f<<9) + (ln<<3) + e].
__global__ __launch_bounds__(256) void prep_weights(
    const float* __restrict__ qkv_w, const float* __restrict__ proj_w,
    const float* __restrict__ fc1_w, const float* __restrict__ fc2_w,
    u16* __restrict__ qkv_wf, u16* __restrict__ proj_wf,
    u16* __restrict__ fc1_wf, u16* __restrict__ fc2_wf) {
  int t0 = blockIdx.x * 256 + threadIdx.x;
  int stride = gridDim.x * 256;
  for (int i = t0; i < 36 * 6 * 512; i += stride) {
    int f = i >> 9, ln = (i >> 3) & 63, e = i & 7;
    int ct = f / 6, kc = f - ct * 6;
    int n = ct * 16 + (ln & 15), k = kc * 32 + (ln >> 4) * 8 + e;
    qkv_wf[i] = f2bf(qkv_w[k * 576 + n]);
  }
  for (int i = t0; i < 12 * 6 * 512; i += stride) {
    int f = i >> 9, ln = (i >> 3) & 63, e = i & 7;
    int ct = f / 6, kc = f - ct * 6;
    int n = ct * 16 + (ln & 15), k = kc * 32 + (ln >> 4) * 8 + e;
    proj_wf[i] = f2bf(proj_w[k * 192 + n]);
  }
  for (int i = t0; i < 48 * 6 * 512; i += stride) {
    int f = i >> 9, ln = (i >> 3) & 63, e = i & 7;
    int ctg = f / 6, kc = f - ctg * 6;
    int n = ctg * 16 + (ln & 15), k = kc * 32 + (ln >> 4) * 8 + e;
    fc1_wf[i] = f2bf(fc1_w[k * 768 + n]);
  }
  for (int i = t0; i < 24 * 12 * 512; i += stride) {
    int f = i >> 9, ln = (i >> 3) & 63, e = i & 7;
    int g2 = f / 12, ct = f - g2 * 12;
    int n = ct * 16 + (ln & 15), k = g2 * 32 + (ln >> 4) * 8 + e;
    fc2_wf[i] = f2bf(fc2_w[k * 192 + n]);
  }
}

// ---------------- fused LN1(+shift/window gather) + QKV GEMM ----------------
__global__ __launch_bounds__(256) void qkv_ln_kernel(
    const float* __restrict__ x, const float* __restrict__ g,
    const float* __restrict__ bb,
    const u16* __restrict__ qkv_wf, const float* __restrict__ qkv_b,
    u16* __restrict__ qkvb, int rowbase, int wbase) {
  __shared__ __align__(16) u16 sA[128 * 200];
  const int tid = threadIdx.x;
  const int r0 = rowbase + blockIdx.x * 128;

  {
    int r = tid >> 1, half = tid & 1;
    int gr = r0 + r;
    int w = gr / 49, n = gr - w * 49;
    int b = w >> 6, wi = w & 63;
    int rr = n / 7, cc = n - rr * 7;
    int hh = (wi >> 3) * 7 + rr + 3; if (hh >= 56) hh -= 56;
    int ww = (wi & 7) * 7 + cc + 3; if (ww >= 56) ww -= 56;
    const float* src = x + ((size_t)b * 3136 + hh * 56 + ww) * 192 + half * 96;
    float s1 = 0.f, s2 = 0.f;
    #pragma unroll
    for (int i = 0; i < 24; i++) {
      float4 v = ((const float4*)src)[i];
      s1 += v.x + v.y + v.z + v.w;
      s2 += v.x * v.x + v.y * v.y + v.z * v.z + v.w * v.w;
    }
    s1 += __shfl_xor(s1, 1);
    s2 += __shfl_xor(s2, 1);
    float mu = s1 * (1.f / 192.f);
    float var = s2 * (1.f / 192.f) - mu * mu;
    float rs = rsqrtf(var + 1e-5f);
    u16* drow = sA + r * 200 + half * 96;
    #pragma unroll
    for (int i = 0; i < 24; i++) {
      float4 v = ((const float4*)src)[i];
      int c = half * 96 + i * 4;
      ushort4 o;
      o.x = f2bf((v.x - mu) * rs * g[c + 0] + bb[c + 0]);
      o.y = f2bf((v.y - mu) * rs * g[c + 1] + bb[c + 1]);
      o.z = f2bf((v.z - mu) * rs * g[c + 2] + bb[c + 2]);
      o.w = f2bf((v.w - mu) * rs * g[c + 3] + bb[c + 3]);
      *((ushort4*)(drow + i * 4)) = o;
    }
  }
  __syncthreads();

  const int wv = tid >> 6, ln = tid & 63, lrow = ln & 15, quad = ln >> 4;
  const int ln8 = ln << 3;

  u32 qkoff[8], voff[8];
  #pragma unroll
  for (int rt = 0; rt < 2; rt++) {
    #pragma unroll
    for (int reg = 0; reg < 4; reg++) {
      int grow = r0 + 32 * wv + 16 * rt + quad * 4 + reg;
      int w_ = grow / 49, n_ = grow - w_ * 49;
      u32 wb = (u32)(w_ - wbase) * 29568u;
      qkoff[rt * 4 + reg] = wb + (u32)n_ * 32u;
      voff[rt * 4 + reg] = wb + (u32)n_;
    }
  }

  for (int ct = 0; ct < 36; ct++) {
    f32x4 acc0 = (f32x4){0.f, 0.f, 0.f, 0.f};
    f32x4 acc1 = (f32x4){0.f, 0.f, 0.f, 0.f};
    #pragma unroll
    for (int kc = 0; kc < 6; kc++) {
      bf16x8 a0 = *(const bf16x8*)(sA + (32 * wv + lrow) * 200 + kc * 32 + quad * 8);
      bf16x8 a1 = *(const bf16x8*)(sA + (32 * wv + 16 + lrow) * 200 + kc * 32 + quad * 8);
      bf16x8 bw = *(const bf16x8*)(qkv_wf + ((ct * 6 + kc) << 9) + ln8);
      acc0 = MFMA16(a0, bw, acc0);
      acc1 = MFMA16(a1, bw, acc1);
    }
    int sec = ct / 12, ccc = ct - sec * 12;
    int head = ccc >> 1, d0 = (ccc & 1) * 16;
    int col = d0 + lrow;
    float bias = qkv_b[sec * 192 + head * 32 + col];
    u32 hoff = (u32)head * 4928u;
    if (sec < 2) {
      u32 coff = hoff + (u32)sec * 1568u + (u32)col;
      #pragma unroll
      for (int reg = 0; reg < 4; reg++) {
        qkvb[qkoff[reg] + coff] = f2bf(acc0[reg] + bias);
        qkvb[qkoff[4 + reg] + coff] = f2bf(acc1[reg] + bias);
      }
    } else {
      u32 coff = hoff + 3136u + (u32)col * 56u;
      #pragma unroll
      for (int reg = 0; reg < 4; reg++) {
        qkvb[voff[reg] + coff] = f2bf(acc0[reg] + bias);
        qkvb[voff[4 + reg] + coff] = f2bf(acc1[reg] + bias);
      }
    }
  }
}

// ---------------- window attention: 1 block/window, 1 wave/head ----------------
__global__ __launch_bounds__(384) void attn2_kernel(
    const u16* __restrict__ qkvb, u16* __restrict__ attnout, int wbase) {
  __shared__ __align__(16) u16 sP[6 * 64 * 72];
  const int tid = threadIdx.x;
  const int wv = tid >> 6;
  const int ln = tid & 63;
  const int lrow = ln & 15;
  const int quad = ln >> 4;
  const int wl = blockIdx.x;
  const int w = wbase + wl;
  const int wi = w & 63;
  const int wr = wi >> 3, wc = wi & 7;
  const u16* base = qkvb + (size_t)(wl * 6 + wv) * 4928;
  u16* sPw = sP + wv * (64 * 72);
  const f32x4 zero4 = {0.f, 0.f, 0.f, 0.f};

  bf16x8 kf[4];
  #pragma unroll
  for (int rt = 0; rt < 4; rt++)
    kf[rt] = *(const bf16x8*)(base + 1568 + (16 * rt + lrow) * 32 + quad * 8);
  f32x4 S[4][4];
  #pragma unroll
  for (int ct = 0; ct < 4; ct++) {
    bf16x8 qf = *(const bf16x8*)(base + (16 * ct + lrow) * 32 + quad * 8);
    #pragma unroll
    for (int rt = 0; rt < 4; rt++)
      S[rt][ct] = MFMA16(kf[rt], qf, zero4);
  }

  int hbn[4], wbn[4];
  #pragma unroll
  for (int ct = 0; ct < 4; ct++) {
    int n = 16 * ct + lrow;
    int rn = (n * 9363) >> 16;
    int cn = n - 7 * rn;
    hbn[ct] = (wr < 7) ? 0 : ((rn >= 4) ? 2 : 1);
    wbn[ct] = (wc < 7) ? 0 : ((cn >= 4) ? 2 : 1);
  }

  const float scale = 0.17677669529663687f;
  float mx[4] = {-1e30f, -1e30f, -1e30f, -1e30f};
  #pragma unroll
  for (int rt = 0; rt < 4; rt++) {
    #pragma unroll
    for (int reg = 0; reg < 4; reg++) {
      int m = 16 * rt + quad * 4 + reg;
      int rm = (m * 9363) >> 16;
      int cm = m - 7 * rm;
      int hbm = (wr < 7) ? 0 : ((rm >= 4) ? 2 : 1);
      int wbm = (wc < 7) ? 0 : ((cm >= 4) ? 2 : 1);
      bool padm = (m >= 49);
      #pragma unroll
      for (int ct = 0; ct < 4; ct++) {
        float sv = S[rt][ct][reg] * scale +
                   (((hbm != hbn[ct]) || (wbm != wbn[ct])) ? -100.f : 0.f);
        sv = padm ? -1e30f : sv;
        S[rt][ct][reg] = sv;
        mx[ct] = fmaxf(mx[ct], sv);
      }
    }
  }
  #pragma unroll
  for (int ct = 0; ct < 4; ct++) {
    mx[ct] = fmaxf(mx[ct], __shfl_xor(mx[ct], 16));
    mx[ct] = fmaxf(mx[ct], __shfl_xor(mx[ct], 32));
  }
  float sum[4] = {0.f, 0.f, 0.f, 0.f};
  #pragma unroll
  for (int rt = 0; rt < 4; rt++)
    #pragma unroll
    for (int reg = 0; reg < 4; reg++)
      #pragma unroll
      for (int ct = 0; ct < 4; ct++) {
        float e = __expf(S[rt][ct][reg] - mx[ct]);
        S[rt][ct][reg] = e;
        sum[ct] += e;
      }
  float inv[4];
  #pragma unroll
  for (int ct = 0; ct < 4; ct++) {
    sum[ct] += __shfl_xor(sum[ct], 16);
    sum[ct] += __shfl_xor(sum[ct], 32);
    inv[ct] = __builtin_amdgcn_rcpf(sum[ct]);
  }

  #pragma unroll
  for (int rt = 0; rt < 4; rt++) {
    #pragma unroll
    for (int ct = 0; ct < 4; ct++) {
      ushort4 o;
      o.x = f2bf(S[rt][ct][0] * inv[ct]);
      o.y = f2bf(S[rt][ct][1] * inv[ct]);
      o.z = f2bf(S[rt][ct][2] * inv[ct]);
      o.w = f2bf(S[rt][ct][3] * inv[ct]);
      *((ushort4*)(sPw + (16 * ct + lrow) * 72 + 16 * rt + quad * 4)) = o;
    }
  }

  f32x4 accO[4][2];
  #pragma unroll
  for (int rt = 0; rt < 4; rt++)
    #pragma unroll
    for (int cd = 0; cd < 2; cd++) accO[rt][cd] = zero4;
  #pragma unroll
  for (int kc = 0; kc < 2; kc++) {
    bf16x8 vf[2];
    #pragma unroll
    for (int cd = 0; cd < 2; cd++)
      vf[cd] = *(const bf16x8*)(base + 3136 + (16 * cd + lrow) * 56 + kc * 32 + quad * 8);
    #pragma unroll
    for (int rt = 0; rt < 4; rt++) {
      bf16x8 af = *(const bf16x8*)(sPw + (16 * rt + lrow) * 72 + kc * 32 + quad * 8);
      #pragma unroll
      for (int cd = 0; cd < 2; cd++)
        accO[rt][cd] = MFMA16(af, vf[cd], accO[rt][cd]);
    }
  }

  #pragma unroll
  for (int rt = 0; rt < 4; rt++) {
    #pragma unroll
    for (int reg = 0; reg < 4; reg++) {
      int n = 16 * rt + quad * 4 + reg;
      if (n < 49) {
        #pragma unroll
        for (int cd = 0; cd < 2; cd++)
          attnout[(size_t)(w * 49 + n) * 192 + wv * 32 + 16 * cd + lrow] =
              f2bf(accO[rt][cd][reg]);
      }
    }
  }
}

// ---------------- fused proj + LN2 + MLP + residual + scatter ----------------
// 256 thr, 64 rows/block, column-split (wave owns 48 cols of all 64 rows).
// launch_bounds(256,2): ~256 unified regs/thread so xr+accO+fc1b/fc2b all
// fit WITHOUT scratch spill (R6's (256,3) cap forced a silent 77MB x2 spill
// -- diagnosed via FETCH/WRITE excess). proj weights load inline (one-shot
// phase); fc1b/fc2b keep the one-phase-ahead register prefetch.
__global__ __launch_bounds__(256, 2) void projmlp_kernel(
    const u16* __restrict__ attnout, const u16* __restrict__ proj_wf,
    const float* __restrict__ proj_b,
    const float* __restrict__ g, const float* __restrict__ bb,
    const u16* __restrict__ fc1_wf, const float* __restrict__ fc1_b,
    const u16* __restrict__ fc2_wf, const float* __restrict__ fc2_b,
    float* __restrict__ out) {
  __shared__ __align__(16) u16 sA[64 * 200];
  __shared__ __align__(16) u16 sT[2 * 64 * 72];
  __shared__ __align__(16) float sStat[64 * 8];
  const int tid = threadIdx.x;
  const int wv = tid >> 6, ln = tid & 63, lrow = ln & 15, quad = ln >> 4;
  const int ln8 = ln << 3;
  const int r0 = blockIdx.x * 64;
  const f32x4 zero4 = {0.f, 0.f, 0.f, 0.f};

  // stage attnout rows -> sA
  {
    const u32* src = (const u32*)(attnout + (size_t)r0 * 192);
    u32* dst = (u32*)sA;
    #pragma unroll
    for (int i = 0; i < 24; i++) {
      int idx = tid + i * 256;
      int r = idx / 96, c = idx - r * 96;
      dst[r * 100 + c] = src[idx];
    }
  }
  __syncthreads();   // B1

  // proj GEMM (weights inline; one-shot phase)
  f32x4 xr[4][3];
  #pragma unroll
  for (int rt = 0; rt < 4; rt++)
    #pragma unroll
    for (int ct = 0; ct < 3; ct++) xr[rt][ct] = zero4;
  #pragma unroll
  for (int kc = 0; kc < 6; kc++) {
    bf16x8 af[4];
    #pragma unroll
    for (int rt = 0; rt < 4; rt++)
      af[rt] = *(const bf16x8*)(sA + (16 * rt + lrow) * 200 + kc * 32 + quad * 8);
    #pragma unroll
    for (int ct = 0; ct < 3; ct++) {
      bf16x8 b = *(const bf16x8*)(proj_wf + (((wv * 3 + ct) * 6 + kc) << 9) + ln8);
      #pragma unroll
      for (int rt = 0; rt < 4; rt++)
        xr[rt][ct] = MFMA16(af[rt], b, xr[rt][ct]);
    }
  }
  #pragma unroll
  for (int ct = 0; ct < 3; ct++) {
    float pbias = proj_b[wv * 48 + ct * 16 + lrow];
    #pragma unroll
    for (int rt = 0; rt < 4; rt++) {
      xr[rt][ct][0] += pbias; xr[rt][ct][1] += pbias;
      xr[rt][ct][2] += pbias; xr[rt][ct][3] += pbias;
    }
  }

  // prefetch first MLP weights (consumed after B3/B4)
  bf16x8 fc1b[6], fc2b[6];
  #pragma unroll
  for (int kc = 0; kc < 6; kc++)
    fc1b[kc] = *(const bf16x8*)(fc1_wf + (((0 * 4 + wv) * 6 + kc) << 9) + ln8);
  #pragma unroll
  for (int kc2 = 0; kc2 < 2; kc2++)
    #pragma unroll
    for (int ct = 0; ct < 3; ct++)
      fc2b[kc2 * 3 + ct] = *(const bf16x8*)(fc2_wf +
          (((0 * 2 + kc2) * 12 + wv * 3 + ct) << 9) + ln8);

  // LN2 stats (partial 48 cols/wave, exchange via LDS)
  {
    float ps1[4][4], ps2[4][4];
    #pragma unroll
    for (int rt = 0; rt < 4; rt++)
      #pragma unroll
      for (int reg = 0; reg < 4; reg++) {
        float a = xr[rt][0][reg] + xr[rt][1][reg] + xr[rt][2][reg];
        float b = xr[rt][0][reg] * xr[rt][0][reg] +
                  xr[rt][1][reg] * xr[rt][1][reg] +
                  xr[rt][2][reg] * xr[rt][2][reg];
        ps1[rt][reg] = a; ps2[rt][reg] = b;
      }
    #pragma unroll
    for (int m = 1; m <= 8; m <<= 1)
      #pragma unroll
      for (int rt = 0; rt < 4; rt++)
        #pragma unroll
        for (int reg = 0; reg < 4; reg++) {
          ps1[rt][reg] += __shfl_xor(ps1[rt][reg], m);
          ps2[rt][reg] += __shfl_xor(ps2[rt][reg], m);
        }
    if (lrow == 0) {
      #pragma unroll
      for (int rt = 0; rt < 4; rt++)
        #pragma unroll
        for (int reg = 0; reg < 4; reg++) {
          int row = 16 * rt + 4 * quad + reg;
          *(float2*)&sStat[row * 8 + wv * 2] =
              make_float2(ps1[rt][reg], ps2[rt][reg]);
        }
    }
  }
  __syncthreads();   // B2

  // finish LN2 -> sA (normalized bf16 overwrites staged input)
  {
    float gc[3], bc[3];
    #pragma unroll
    for (int ct = 0; ct < 3; ct++) {
      int col = wv * 48 + ct * 16 + lrow;
      gc[ct] = g[col]; bc[ct] = bb[col];
    }
    #pragma unroll
    for (int rt = 0; rt < 4; rt++) {
      float mu_[4], rs_[4];
      #pragma unroll
      for (int reg = 0; reg < 4; reg++) {
        int row = 16 * rt + 4 * quad + reg;
        f32x4 q0 = *(const f32x4*)&sStat[row * 8];
        f32x4 q1 = *(const f32x4*)&sStat[row * 8 + 4];
        float s1 = q0[0] + q0[2] + q1[0] + q1[2];
        float s2 = q0[1] + q0[3] + q1[1] + q1[3];
        float mu = s1 * (1.f / 192.f);
        float var = s2 * (1.f / 192.f) - mu * mu;
        mu_[reg] = mu; rs_[reg] = rsqrtf(var + 1e-5f);
      }
      #pragma unroll
      for (int ct = 0; ct < 3; ct++) {
        int col = wv * 48 + ct * 16 + lrow;
        #pragma unroll
        for (int reg = 0; reg < 4; reg++) {
          int row = 16 * rt + 4 * quad + reg;
          sA[row * 200 + col] =
              f2bf((xr[rt][ct][reg] - mu_[reg]) * rs_[reg] * gc[ct] + bc[ct]);
        }
      }
    }
  }
  __syncthreads();   // B3

  f32x4 accO[4][3];
  #pragma unroll
  for (int rt = 0; rt < 4; rt++)
    #pragma unroll
    for (int ct = 0; ct < 3; ct++) accO[rt][ct] = zero4;

  auto FC1 = [&](int ch, u16* dst) {
    f32x4 accT[4] = {zero4, zero4, zero4, zero4};
    #pragma unroll
    for (int kc = 0; kc < 6; kc++) {
      bf16x8 af[4];
      #pragma unroll
      for (int rt = 0; rt < 4; rt++)
        af[rt] = *(const bf16x8*)(sA + (16 * rt + lrow) * 200 + kc * 32 + quad * 8);
      #pragma unroll
      for (int rt = 0; rt < 4; rt++)
        accT[rt] = MFMA16(af[rt], fc1b[kc], accT[rt]);
    }
    float b1 = fc1_b[ch * 64 + wv * 16 + lrow];
    #pragma unroll
    for (int rt = 0; rt < 4; rt++)
      #pragma unroll
      for (int reg = 0; reg < 4; reg++) {
        float v = accT[rt][reg] + b1;
        dst[(16 * rt + 4 * quad + reg) * 72 + wv * 16 + lrow] = f2bf(gelu_f(v));
      }
  };
  auto FC2 = [&](const u16* src) {
    #pragma unroll
    for (int kc2 = 0; kc2 < 2; kc2++) {
      bf16x8 ta[4];
      #pragma unroll
      for (int rt = 0; rt < 4; rt++)
        ta[rt] = *(const bf16x8*)(src + (16 * rt + lrow) * 72 + kc2 * 32 + quad * 8);
      #pragma unroll
      for (int ct = 0; ct < 3; ct++)
        #pragma unroll
        for (int rt = 0; rt < 4; rt++)
          accO[rt][ct] = MFMA16(ta[rt], fc2b[kc2 * 3 + ct], accO[rt][ct]);
    }
  };

  FC1(0, sT);          // consumes fc1b(0)
  __syncthreads();     // B4
  for (int ch = 0; ch < 12; ch++) {
    if (ch < 11) {     // prefetch fc1 weights for ch+1, pinned before FC2
      #pragma unroll
      for (int kc = 0; kc < 6; kc++)
        fc1b[kc] = *(const bf16x8*)(fc1_wf +
            ((((ch + 1) * 4 + wv) * 6 + kc) << 9) + ln8);
      __builtin_amdgcn_sched_barrier(0);
    }
    const u16* cur = sT + (ch & 1) * (64 * 72);
    u16* nxt = sT + ((ch + 1) & 1) * (64 * 72);
    FC2(cur);          // consumes fc2b(ch)
    if (ch < 11) {     // prefetch fc2 weights for ch+1 (crosses the barrier)
      #pragma unroll
      for (int kc2 = 0; kc2 < 2; kc2++)
        #pragma unroll
        for (int ct = 0; ct < 3; ct++)
          fc2b[kc2 * 3 + ct] = *(const bf16x8*)(fc2_wf +
              ((((ch + 1) * 2 + kc2) * 12 + wv * 3 + ct) << 9) + ln8);
      FC1(ch + 1, nxt);  // consumes fc1b(ch+1) prefetched above
    }
    __syncthreads();
  }

  // epilogue: single fused write out = xr + accO + fc2_b (scattered)
  float fb[3];
  #pragma unroll
  for (int ct = 0; ct < 3; ct++) fb[ct] = fc2_b[wv * 48 + ct * 16 + lrow];
  #pragma unroll
  for (int rt = 0; rt < 4; rt++) {
    #pragma unroll
    for (int reg = 0; reg < 4; reg++) {
      int gr = r0 + 16 * rt + 4 * quad + reg;
      int w = gr / 49, n = gr - w * 49;
      int b = w >> 6, wi = w & 63;
      int rr = n / 7;
      int hh = (wi >> 3) * 7 + rr + 3; if (hh >= 56) hh -= 56;
      int ww = (wi & 7) * 7 + (n - rr * 7) + 3; if (ww >= 56) ww -= 56;
      float* orow = out + ((size_t)b * 3136 + hh * 56 + ww) * 192;
      #pragma unroll
      for (int ct = 0; ct < 3; ct++) {
        int col = wv * 48 + ct * 16 + lrow;
        orow[col] = xr[rt][ct][reg] + accO[rt][ct][reg] + fb[ct];
      }
    }
  }
}

extern "C" void kernel_launch(void* const* d_in, const int* in_sizes, int n_in,
                              void* d_out, int out_size, void* d_ws, size_t ws_size,
                              hipStream_t stream) {
  const float* x      = (const float*)d_in[0];
  const float* qkv_w  = (const float*)d_in[1];
  const float* qkv_b  = (const float*)d_in[2];
  const float* proj_w = (const float*)d_in[3];
  const float* proj_b = (const float*)d_in[4];
  const float* n1_g   = (const float*)d_in[5];
  const float* n1_b   = (const float*)d_in[6];
  const float* n2_g   = (const float*)d_in[7];
  const float* n2_b   = (const float*)d_in[8];
  const float* fc1_w  = (const float*)d_in[9];
  const float* fc1_b  = (const float*)d_in[10];
  const float* fc2_w  = (const float*)d_in[11];
  const float* fc2_b  = (const float*)d_in[12];
  float* out = (float*)d_out;
  char* ws = (char*)d_ws;

  // workspace layout (bytes)
  u16* qkvb    = (u16*)(ws + 0);            // 60,555,264
  u16* attnout = (u16*)(ws + 60555264);     // 38,535,168 -> ends 99,090,432
  u16* qkv_wf  = (u16*)(ws + 99090432);     // 221,184
  u16* proj_wf = (u16*)(ws + 99311616);     // 73,728
  u16* fc1_wf  = (u16*)(ws + 99385344);     // 294,912
  u16* fc2_wf  = (u16*)(ws + 99680256);     // 294,912 -> ends 99,975,168

  prep_weights<<<256, 256, 0, stream>>>(qkv_w, proj_w, fc1_w, fc2_w,
                                        qkv_wf, proj_wf, fc1_wf, fc2_wf);
  for (int hf = 0; hf < 2; hf++) {
    qkv_ln_kernel<<<392, 256, 0, stream>>>(x, n1_g, n1_b, qkv_wf, qkv_b,
                                           qkvb, hf * 50176, hf * 1024);
    attn2_kernel<<<1024, 384, 0, stream>>>(qkvb, attnout, hf * 1024);
  }
  projmlp_kernel<<<1568, 256, 0, stream>>>(attnout, proj_wf, proj_b,
                                           n2_g, n2_b, fc1_wf, fc1_b,
                                           fc2_wf, fc2_b, out);
}